// Round 1
// baseline (237.993 us; speedup 1.0000x reference)
//
#include <hip/hip_runtime.h>
#include <math.h>

#define B 128
#define T 1024
#define H 256
#define L 16
#define INV_TEMP (1.0f/0.07f)
#define NEG_INF -1e30f

// ws layout (only seg<nseg regions are ever written/read -> no memset):
//   ws_pp   : float[B][4][L][H]   per-seg prototype partial sums   8 MB
//   ws_cntp : int[B][4][L]        per-seg label counts             32 KB
// (ws_dots eliminated: dots+loss fused, dot[L] stays in registers)

// ---------------------------------------------------------------------------
// Kernel 1: prototype partial sums. grid = B * 2 chunks * 4 segs = 1024 blocks.
// Block owns a disjoint [b][seg][L][chunk*128..+128) slice -> plain stores, no
// atomics. Invalid segments exit immediately (consumers skip seg >= nseg).
// Block 0 also zeroes the output scalar (stream order makes this safe; removes
// the separate hipMemsetAsync dispatch).
__global__ __launch_bounds__(256) void proto_kernel(
    const float* __restrict__ feat, const int* __restrict__ dlen,
    const int* __restrict__ labels, float* __restrict__ ws_pp,
    int* __restrict__ ws_cntp, float* __restrict__ out) {
  __shared__ float acc[4][L * 128];   // 32 KB, wave-private slabs
  __shared__ int labs[256];
  __shared__ int cnt[L];

  const int bx = blockIdx.x;
  if (bx == 0 && threadIdx.x == 0) out[0] = 0.f;   // replaces memset dispatch

  const int b = bx >> 3;
  const int chunk = (bx >> 2) & 1;
  const int seg = bx & 3;
  const int tid = threadIdx.x;
  const int w = tid >> 6;
  const int lane = tid & 63;

  const int len = dlen[b];
  if (seg * 256 >= len) return;   // fully invalid segment: nothing published

  for (int i = tid; i < 4 * L * 128; i += 256) ((float*)acc)[i] = 0.f;
  labs[tid] = labels[(size_t)b * T + seg * 256 + tid];
  if (tid < L) cnt[tid] = 0;
  __syncthreads();

  if (chunk == 0 && (seg * 256 + tid) < len) atomicAdd(&cnt[labs[tid]], 1);

  int nt = len - seg * 256 - w * 64;   // tokens this wave processes
  if (nt > 64) nt = 64;
  const float2* fbase = (const float2*)(feat +
      ((size_t)b * T + seg * 256 + w * 64) * H + chunk * 128);
  float* a = acc[w];

  int j = 0;
  for (; j + 4 <= nt; j += 4) {
    float2 f0 = fbase[(size_t)(j + 0) * (H / 2) + lane];
    float2 f1 = fbase[(size_t)(j + 1) * (H / 2) + lane];
    float2 f2 = fbase[(size_t)(j + 2) * (H / 2) + lane];
    float2 f3 = fbase[(size_t)(j + 3) * (H / 2) + lane];
    const int l0 = labs[w * 64 + j + 0];
    const int l1 = labs[w * 64 + j + 1];
    const int l2 = labs[w * 64 + j + 2];
    const int l3 = labs[w * 64 + j + 3];
    float2* p0 = (float2*)&a[l0 * 128 + lane * 2];
    { float2 v = *p0; v.x += f0.x; v.y += f0.y; *p0 = v; }
    float2* p1 = (float2*)&a[l1 * 128 + lane * 2];
    { float2 v = *p1; v.x += f1.x; v.y += f1.y; *p1 = v; }
    float2* p2 = (float2*)&a[l2 * 128 + lane * 2];
    { float2 v = *p2; v.x += f2.x; v.y += f2.y; *p2 = v; }
    float2* p3 = (float2*)&a[l3 * 128 + lane * 2];
    { float2 v = *p3; v.x += f3.x; v.y += f3.y; *p3 = v; }
  }
  for (; j < nt; ++j) {
    float2 f = fbase[(size_t)j * (H / 2) + lane];
    const int lab = labs[w * 64 + j];
    float2* p = (float2*)&a[lab * 128 + lane * 2];
    float2 v = *p; v.x += f.x; v.y += f.y; *p = v;
  }
  __syncthreads();

  float* op = ws_pp + (((size_t)b * 4 + seg) * L) * H + chunk * 128;
  for (int e = tid; e < L * 128; e += 256) {
    const float s = acc[0][e] + acc[1][e] + acc[2][e] + acc[3][e];
    op[(e >> 7) * H + (e & 127)] = s;
  }
  if (chunk == 0 && tid < L) ws_cntp[(b * 4 + seg) * L + tid] = cnt[tid];
}

// ---------------------------------------------------------------------------
// Kernel 2 (fused dots+loss): grid = B*4 segment blocks, 256 thr, 1 token per
// thread, FULL H=256 per token -> dot[L] lives in registers, so log-softmax +
// masked mean happen here and ws_dots disappears. Prototypes (L*H = 16 KB)
// staged once in LDS; proto reads are wave-uniform b128 broadcasts (each feeds
// 4 FMAs). Per-thread global loads walk the token's own row in 64B sectors
// (full line utilization via q-unroll, same as the previous dots kernel).
__global__ __launch_bounds__(256) void dotsloss_kernel(
    const float* __restrict__ feat, const int* __restrict__ dlen,
    const int* __restrict__ labels, const float* __restrict__ ws_pp,
    const int* __restrict__ ws_cntp, float* __restrict__ out) {
  __shared__ float pr[L * H];   // 16 KB prototypes, full H
  __shared__ int cnts[L];
  __shared__ float red[256];

  const int b = blockIdx.x >> 2;
  const int seg = blockIdx.x & 3;
  const int tid = threadIdx.x;

  const int len = dlen[b];
  if (seg * 256 >= len) return;        // contributes exactly 0
  const int nseg = (len + 255) >> 8;   // 1..4 valid segments

  if (tid < L) {
    const int* cp = ws_cntp + b * 4 * L + tid;
    int c = 0;
    for (int s = 0; s < nseg; ++s) c += cp[s * L];
    cnts[tid] = c;
  }
  __syncthreads();

  // assemble prototypes: sum valid segment partials, divide by count
  const float* gp = ws_pp + (size_t)b * 4 * L * H;
  for (int i = tid; i < L * H; i += 256) {
    const int l = i >> 8;              // H = 256
    float s = 0.f;
    for (int sg = 0; sg < nseg; ++sg) s += gp[(sg * L + l) * H + (i & (H - 1))];
    const int cn = cnts[l];
    pr[i] = s * (cn > 0 ? 1.f / (float)cn : 0.f);
  }
  __syncthreads();

  const int t = seg * 256 + tid;
  float tok = 0.f;

  if (t < len) {
    const float4* f4 = (const float4*)(feat + ((size_t)b * T + t) * H);
    float dot[L];
#pragma unroll
    for (int l = 0; l < L; ++l) dot[l] = 0.f;

#pragma unroll 4
    for (int cb = 0; cb < 16; ++cb) {  // 16-float chunks of the token row
      float4 f[4];
#pragma unroll
      for (int q = 0; q < 4; ++q) f[q] = f4[cb * 4 + q];
#pragma unroll
      for (int q = 0; q < 4; ++q) {
#pragma unroll
        for (int l = 0; l < L; ++l) {
          const float4 p = *(const float4*)&pr[l * H + cb * 16 + q * 4];
          dot[l] += f[q].x * p.x + f[q].y * p.y +
                    f[q].z * p.z + f[q].w * p.w;
        }
      }
    }

    float lg[L];
#pragma unroll
    for (int l = 0; l < L; ++l)
      lg[l] = (cnts[l] > 0) ? dot[l] * INV_TEMP : NEG_INF;
    float m = lg[0];
#pragma unroll
    for (int l = 1; l < L; ++l) m = fmaxf(m, lg[l]);
    float se = 0.f;
#pragma unroll
    for (int l = 0; l < L; ++l) se += expf(lg[l] - m);
    const float lsp = m + logf(se);

    const int lab = labels[(size_t)b * T + t];
    float pos = 0.f;
#pragma unroll
    for (int l = 0; l < L; ++l) pos += (l == lab) ? lg[l] : 0.f;  // no dyn idx

    tok = lsp - pos;
  }

  red[tid] = tok;
  __syncthreads();
#pragma unroll
  for (int s = 128; s > 0; s >>= 1) {
    if (tid < s) red[tid] += red[tid + s];
    __syncthreads();
  }
  if (tid == 0) atomicAdd(out, red[0] / ((float)len * (float)B));
}

extern "C" void kernel_launch(void* const* d_in, const int* in_sizes, int n_in,
                              void* d_out, int out_size, void* d_ws, size_t ws_size,
                              hipStream_t stream) {
  const float* feat = (const float*)d_in[0];
  const int* dlen = (const int*)d_in[1];
  const int* labels = (const int*)d_in[2];
  float* out = (float*)d_out;

  float* ws_pp = (float*)d_ws;                           // B*4*L*H floats
  int* ws_cntp = (int*)(ws_pp + (size_t)B * 4 * L * H);  // B*4*L ints

  proto_kernel<<<B * 8, 256, 0, stream>>>(feat, dlen, labels, ws_pp, ws_cntp, out);
  dotsloss_kernel<<<B * 4, 256, 0, stream>>>(feat, dlen, labels, ws_pp, ws_cntp, out);
}